// Round 1
// baseline (2778.617 us; speedup 1.0000x reference)
//
#include <hip/hip_runtime.h>
#include <math.h>

#define NN 100000
#define EE 800000
#define FIN 256
#define CH 64      // HID
#define NHEAD 4
#define C1 256     // H*HID
#define BN_EPS 1e-5f
#define NEG_SLOPE 0.2f

// ---------- helpers ----------
__device__ __forceinline__ unsigned enc_f(float f) {
    unsigned u = __float_as_uint(f);
    return (u & 0x80000000u) ? ~u : (u | 0x80000000u);
}
__device__ __forceinline__ float dec_f(unsigned u) {
    return (u & 0x80000000u) ? __uint_as_float(u ^ 0x80000000u) : __uint_as_float(~u);
}
#define ENC_NEG_INF 0x007FFFFFu

__device__ __forceinline__ void get_edge(const int* __restrict__ ei, int e, int& s, int& d) {
    if (e < EE) { s = ei[e]; d = ei[EE + e]; }
    else        { s = e - EE; d = s; }
}

// ---------- degree ----------
__global__ void deg_kernel(const int* __restrict__ ei, float* __restrict__ deg) {
    int t = blockIdx.x * 256 + threadIdx.x;
    if (t < EE) atomicAdd(&deg[ei[EE + t]], 1.0f);
}
__global__ void dinv_kernel(float* __restrict__ deg) {
    int i = blockIdx.x * 256 + threadIdx.x;
    if (i < NN) {
        float d = deg[i] + 1.0f;           // self loop
        deg[i] = rsqrtf(fmaxf(d, 1.0f));
    }
}

// ---------- tiled fp32 GEMM: C[N x K] = A[N x M] @ B[M x K] ----------
// grid(K/64, ceil(N/64)), block 256
__global__ __launch_bounds__(256) void gemm_tiled(
        const float* __restrict__ A, const float* __restrict__ B,
        float* __restrict__ C, int M, int K) {
    __shared__ float As[16][64];
    __shared__ float Bs[16][64];
    int t = threadIdx.x;
    int rowBase = blockIdx.y * 64;
    int colBase = blockIdx.x * 64;
    int ty = t >> 4, tx = t & 15;
    float acc[4][4] = {};
    int arow = t >> 2;
    int ak4 = (t & 3) * 4;
    int bkk = t >> 4;
    int bc4 = (t & 15) * 4;
    for (int k0 = 0; k0 < M; k0 += 16) {
        float4 av = make_float4(0.f, 0.f, 0.f, 0.f);
        int gr = rowBase + arow;
        if (gr < NN) av = *(const float4*)&A[(long)gr * M + k0 + ak4];
        As[ak4 + 0][arow] = av.x;
        As[ak4 + 1][arow] = av.y;
        As[ak4 + 2][arow] = av.z;
        As[ak4 + 3][arow] = av.w;
        float4 bv = *(const float4*)&B[(long)(k0 + bkk) * K + colBase + bc4];
        *(float4*)&Bs[bkk][bc4] = bv;
        __syncthreads();
#pragma unroll
        for (int kk = 0; kk < 16; ++kk) {
            float a0 = As[kk][ty * 4 + 0], a1 = As[kk][ty * 4 + 1];
            float a2 = As[kk][ty * 4 + 2], a3 = As[kk][ty * 4 + 3];
            float b0 = Bs[kk][tx * 4 + 0], b1 = Bs[kk][tx * 4 + 1];
            float b2 = Bs[kk][tx * 4 + 2], b3 = Bs[kk][tx * 4 + 3];
            acc[0][0] += a0 * b0; acc[0][1] += a0 * b1; acc[0][2] += a0 * b2; acc[0][3] += a0 * b3;
            acc[1][0] += a1 * b0; acc[1][1] += a1 * b1; acc[1][2] += a1 * b2; acc[1][3] += a1 * b3;
            acc[2][0] += a2 * b0; acc[2][1] += a2 * b1; acc[2][2] += a2 * b2; acc[2][3] += a2 * b3;
            acc[3][0] += a3 * b0; acc[3][1] += a3 * b1; acc[3][2] += a3 * b2; acc[3][3] += a3 * b3;
        }
        __syncthreads();
    }
#pragma unroll
    for (int j = 0; j < 4; ++j) {
        int gr = rowBase + ty * 4 + j;
        if (gr < NN) {
            float4 o = make_float4(acc[j][0], acc[j][1], acc[j][2], acc[j][3]);
            *(float4*)&C[(long)gr * K + colBase + tx * 4] = o;
        }
    }
}

// ---------- GCN scatter ----------
__global__ void gcn_scatter(const int* __restrict__ ei, const float* __restrict__ dinv,
                            const float* __restrict__ h0, float* __restrict__ agg) {
    int gid = blockIdx.x * 4 + (threadIdx.x >> 6);
    if (gid >= EE) return;
    int c = threadIdx.x & 63;
    int s = ei[gid], d = ei[EE + gid];
    float nrm = dinv[s] * dinv[d];
    atomicAdd(&agg[d * 64 + c], h0[s * 64 + c] * nrm);
}
__global__ void gcn_self(const float* __restrict__ dinv, const float* __restrict__ h0,
                         float* __restrict__ agg) {
    int idx = blockIdx.x * 256 + threadIdx.x;
    if (idx < NN * 64) {
        int i = idx >> 6;
        float di = dinv[i];
        agg[idx] += h0[idx] * di * di;
    }
}

// ---------- BatchNorm ----------
// mode 0: v = relu(x + b)   (GCN path; no post-activation in apply)
// mode 1: v = x + b         (GAT path; ELU post-activation in apply)
__global__ void bn_stats(const float* __restrict__ x, const float* __restrict__ bias,
                         float* __restrict__ sums, float* __restrict__ sumsq,
                         int C, int relu_mode) {
    int col = threadIdx.x & (C - 1);
    int sub = threadIdx.x / C;
    int stride = 256 / C;
    int r0 = blockIdx.x * 256;
    int r1 = min(r0 + 256, NN);
    float b = bias[col];
    float s = 0.f, ss = 0.f;
    for (int r = r0 + sub; r < r1; r += stride) {
        float v = x[(long)r * C + col] + b;
        if (relu_mode) v = fmaxf(v, 0.f);
        s += v; ss += v * v;
    }
    atomicAdd(&sums[col], s);
    atomicAdd(&sumsq[col], ss);
}
__global__ void bn_finalize(const float* __restrict__ sums, const float* __restrict__ sumsq,
                            const float* __restrict__ g, const float* __restrict__ beta,
                            float* __restrict__ scale, float* __restrict__ shift, int C) {
    int c = threadIdx.x;
    if (c < C) {
        float mean = sums[c] / (float)NN;
        float var = sumsq[c] / (float)NN - mean * mean;
        float sc = g[c] * rsqrtf(var + BN_EPS);
        scale[c] = sc;
        shift[c] = beta[c] - mean * sc;
    }
}
__global__ void bn_apply(float* __restrict__ x, const float* __restrict__ bias,
                         const float* __restrict__ scale, const float* __restrict__ shift,
                         int C, int mode) {
    long total = (long)NN * C;
    long idx = (long)blockIdx.x * 256 + threadIdx.x;
    if (idx < total) {
        int c = (int)(idx & (C - 1));
        float v = x[idx] + bias[c];
        if (mode == 0) v = fmaxf(v, 0.f);
        v = scale[c] * v + shift[c];
        if (mode == 1) v = (v > 0.f) ? v : expm1f(v);
        x[idx] = v;
    }
}

// ---------- GAT ----------
// one block (256 thr) per node: per-head dot products
__global__ void gat_alpha(const float* __restrict__ h, const float* __restrict__ a_src,
                          const float* __restrict__ a_dst,
                          float* __restrict__ alpha_s, float* __restrict__ alpha_d) {
    int n = blockIdx.x;
    int t = threadIdx.x;
    float hv = h[(long)n * 256 + t];
    float vs = hv * a_src[t];
    float vd = hv * a_dst[t];
    for (int off = 32; off > 0; off >>= 1) {
        vs += __shfl_down(vs, off);
        vd += __shfl_down(vd, off);
    }
    if ((t & 63) == 0) {
        int head = t >> 6;
        alpha_s[n * 4 + head] = vs;
        alpha_d[n * 4 + head] = vd;
    }
}
__global__ void emax_init(unsigned* __restrict__ emaxU) {
    int i = blockIdx.x * 256 + threadIdx.x;
    if (i < NN * 4) emaxU[i] = ENC_NEG_INF;
}
__global__ void gat_edge_max(const int* __restrict__ ei, const float* __restrict__ as,
                             const float* __restrict__ ad, unsigned* __restrict__ emaxU) {
    int tid = blockIdx.x * 256 + threadIdx.x;
    if (tid >= (EE + NN) * 4) return;
    int e = tid >> 2, h = tid & 3;
    int s, d; get_edge(ei, e, s, d);
    float ev = as[s * 4 + h] + ad[d * 4 + h];
    ev = (ev > 0.f) ? ev : NEG_SLOPE * ev;
    atomicMax(&emaxU[d * 4 + h], enc_f(ev));
}
__global__ void gat_edge_w(const int* __restrict__ ei, const float* __restrict__ as,
                           const float* __restrict__ ad, const unsigned* __restrict__ emaxU,
                           float* __restrict__ wbuf, float* __restrict__ wsum) {
    int tid = blockIdx.x * 256 + threadIdx.x;
    if (tid >= (EE + NN) * 4) return;
    int e = tid >> 2, h = tid & 3;
    int s, d; get_edge(ei, e, s, d);
    float ev = as[s * 4 + h] + ad[d * 4 + h];
    ev = (ev > 0.f) ? ev : NEG_SLOPE * ev;
    float m = dec_f(emaxU[d * 4 + h]);
    float w = expf(ev - m);
    wbuf[tid] = w;
    atomicAdd(&wsum[d * 4 + h], w);
}
// one block (256 thr) per edge
__global__ void gat_aggregate(const int* __restrict__ ei, const float* __restrict__ h,
                              const float* __restrict__ wbuf, const float* __restrict__ wsum,
                              float* __restrict__ acc) {
    int e = blockIdx.x;
    int t = threadIdx.x;
    int s, d; get_edge(ei, e, s, d);
    int head = t >> 6;
    float att = wbuf[e * 4 + head] / wsum[d * 4 + head];
    atomicAdd(&acc[(long)d * 256 + t], att * h[(long)s * 256 + t]);
}

// ---------- launch ----------
extern "C" void kernel_launch(void* const* d_in, const int* in_sizes, int n_in,
                              void* d_out, int out_size, void* d_ws, size_t ws_size,
                              hipStream_t stream) {
    const float* x      = (const float*)d_in[0];
    const int*   ei     = (const int*)d_in[1];
    const float* W_gcn  = (const float*)d_in[2];
    const float* b_gcn  = (const float*)d_in[3];
    const float* g0     = (const float*)d_in[4];
    const float* beta0  = (const float*)d_in[5];
    const float* W1     = (const float*)d_in[6];
    const float* a_src1 = (const float*)d_in[7];
    const float* a_dst1 = (const float*)d_in[8];
    const float* b1     = (const float*)d_in[9];
    const float* g1     = (const float*)d_in[10];
    const float* beta1  = (const float*)d_in[11];
    const float* W2     = (const float*)d_in[12];
    const float* a_src2 = (const float*)d_in[13];
    const float* a_dst2 = (const float*)d_in[14];
    const float* b2     = (const float*)d_in[15];
    const float* g2     = (const float*)d_in[16];
    const float* beta2  = (const float*)d_in[17];

    float* ws = (float*)d_ws;
    const long N = NN;
    float*    dinv    = ws;                       // N
    // region overlaying h0 (h0 dead after GCN scatter)
    float*    alpha_s = ws + N;                   // 4N
    float*    alpha_d = alpha_s + 4 * N;          // 4N
    unsigned* emaxU   = (unsigned*)(alpha_d + 4 * N); // 4N
    float*    wsum    = (float*)emaxU + 4 * N;    // 4N
    float*    wbuf    = wsum + 4 * N;             // 4*(E+N) = 36N
    float*    sums    = wbuf + 4L * (EE + NN);    // 256
    float*    sumsq   = sums + 256;               // 256
    float*    scale   = sumsq + 256;              // 256
    float*    shift   = scale + 256;              // 256
    float*    h0      = ws + N;                   // 64N (same region as above)
    float*    agg0    = ws + 65 * N;              // 64N  -> x1
    float*    h1      = ws + 129 * N;             // 256N -> also h2
    float*    acc1    = ws + 385 * N;             // 256N -> x2
    float*    acc2    = (float*)d_out;            // 256N

    const int BLK = 256;
    dim3 blk(BLK);

    // ===== degrees =====
    hipMemsetAsync(dinv, 0, N * sizeof(float), stream);
    deg_kernel<<<(EE + BLK - 1) / BLK, blk, 0, stream>>>(ei, dinv);
    dinv_kernel<<<(NN + BLK - 1) / BLK, blk, 0, stream>>>(dinv);

    // ===== GCN =====
    gemm_tiled<<<dim3(CH / 64, (NN + 63) / 64), blk, 0, stream>>>(x, W_gcn, h0, FIN, CH);
    hipMemsetAsync(agg0, 0, 64 * N * sizeof(float), stream);
    gcn_scatter<<<(EE + 3) / 4, blk, 0, stream>>>(ei, dinv, h0, agg0);
    gcn_self<<<(NN * 64) / BLK, blk, 0, stream>>>(dinv, h0, agg0);
    hipMemsetAsync(sums, 0, 512 * sizeof(float), stream);
    bn_stats<<<(NN + 255) / 256, blk, 0, stream>>>(agg0, b_gcn, sums, sumsq, CH, 1);
    bn_finalize<<<1, CH, 0, stream>>>(sums, sumsq, g0, beta0, scale, shift, CH);
    bn_apply<<<(NN * CH + BLK - 1) / BLK, blk, 0, stream>>>(agg0, b_gcn, scale, shift, CH, 0);
    // agg0 is now x1 [N,64]

    // ===== GAT layer 1 =====
    gemm_tiled<<<dim3(C1 / 64, (NN + 63) / 64), blk, 0, stream>>>(agg0, W1, h1, CH, C1);
    gat_alpha<<<NN, blk, 0, stream>>>(h1, a_src1, a_dst1, alpha_s, alpha_d);
    emax_init<<<(NN * 4 + BLK - 1) / BLK, blk, 0, stream>>>(emaxU);
    hipMemsetAsync(wsum, 0, 4 * N * sizeof(float), stream);
    gat_edge_max<<<((EE + NN) * 4 + BLK - 1) / BLK, blk, 0, stream>>>(ei, alpha_s, alpha_d, emaxU);
    gat_edge_w<<<((EE + NN) * 4 + BLK - 1) / BLK, blk, 0, stream>>>(ei, alpha_s, alpha_d, emaxU, wbuf, wsum);
    hipMemsetAsync(acc1, 0, 256 * N * sizeof(float), stream);
    gat_aggregate<<<EE + NN, blk, 0, stream>>>(ei, h1, wbuf, wsum, acc1);
    hipMemsetAsync(sums, 0, 512 * sizeof(float), stream);
    bn_stats<<<(NN + 255) / 256, blk, 0, stream>>>(acc1, b1, sums, sumsq, C1, 0);
    bn_finalize<<<1, C1, 0, stream>>>(sums, sumsq, g1, beta1, scale, shift, C1);
    bn_apply<<<(NN * C1 + BLK - 1) / BLK, blk, 0, stream>>>(acc1, b1, scale, shift, C1, 1);
    // acc1 is now x2 [N,256]

    // ===== GAT layer 2 =====
    gemm_tiled<<<dim3(C1 / 64, (NN + 63) / 64), blk, 0, stream>>>(acc1, W2, h1, C1, C1);
    gat_alpha<<<NN, blk, 0, stream>>>(h1, a_src2, a_dst2, alpha_s, alpha_d);
    emax_init<<<(NN * 4 + BLK - 1) / BLK, blk, 0, stream>>>(emaxU);
    hipMemsetAsync(wsum, 0, 4 * N * sizeof(float), stream);
    gat_edge_max<<<((EE + NN) * 4 + BLK - 1) / BLK, blk, 0, stream>>>(ei, alpha_s, alpha_d, emaxU);
    gat_edge_w<<<((EE + NN) * 4 + BLK - 1) / BLK, blk, 0, stream>>>(ei, alpha_s, alpha_d, emaxU, wbuf, wsum);
    hipMemsetAsync(acc2, 0, (size_t)out_size * sizeof(float), stream);
    gat_aggregate<<<EE + NN, blk, 0, stream>>>(ei, h1, wbuf, wsum, acc2);
    hipMemsetAsync(sums, 0, 512 * sizeof(float), stream);
    bn_stats<<<(NN + 255) / 256, blk, 0, stream>>>(acc2, b2, sums, sumsq, C1, 0);
    bn_finalize<<<1, C1, 0, stream>>>(sums, sumsq, g2, beta2, scale, shift, C1);
    bn_apply<<<(NN * C1 + BLK - 1) / BLK, blk, 0, stream>>>(acc2, b2, scale, shift, C1, 1);
}

// Round 2
// 1693.416 us; speedup vs baseline: 1.6408x; 1.6408x over previous
//
#include <hip/hip_runtime.h>
#include <math.h>

#define NN 100000
#define EE 800000
#define FIN 256
#define CH 64      // HID
#define NHEAD 4
#define C1 256     // H*HID
#define BN_EPS 1e-5f
#define NEG_SLOPE 0.2f
#define MAXD 64    // LDS cache depth for per-edge attention weights

// ================= CSR build =================
__global__ void hist_kernel(const int* __restrict__ ei, int* __restrict__ deg) {
    int t = blockIdx.x * 256 + threadIdx.x;
    if (t < EE) atomicAdd(&deg[ei[EE + t]], 1);
}
__global__ void dinv_kernel(const int* __restrict__ deg, float* __restrict__ dinv) {
    int i = blockIdx.x * 256 + threadIdx.x;
    if (i < NN) dinv[i] = rsqrtf((float)(deg[i] + 1));  // +1 self loop
}
// per-block exclusive scan of (deg+1); block sums to bsum
__global__ void scan_k1(const int* __restrict__ deg, int* __restrict__ row_start,
                        int* __restrict__ bsum) {
    __shared__ int sh[256];
    int t = threadIdx.x;
    int i = blockIdx.x * 256 + t;
    int v = (i < NN) ? (deg[i] + 1) : 0;
    sh[t] = v;
    __syncthreads();
    for (int off = 1; off < 256; off <<= 1) {
        int add = (t >= off) ? sh[t - off] : 0;
        __syncthreads();
        sh[t] += add;
        __syncthreads();
    }
    if (i < NN) row_start[i] = sh[t] - v;   // exclusive within block
    if (t == 255) bsum[blockIdx.x] = sh[255];
}
__global__ void scan_k2(int* __restrict__ bsum, int nb) {
    __shared__ int sh[512];
    int t = threadIdx.x;
    int v = (t < nb) ? bsum[t] : 0;
    sh[t] = v;
    __syncthreads();
    for (int off = 1; off < 512; off <<= 1) {
        int add = (t >= off) ? sh[t - off] : 0;
        __syncthreads();
        sh[t] += add;
        __syncthreads();
    }
    if (t < nb) bsum[t] = sh[t] - v;        // exclusive
}
__global__ void scan_k3(int* __restrict__ row_start, const int* __restrict__ bsum) {
    int i = blockIdx.x * 256 + threadIdx.x;
    if (i < NN) row_start[i] += bsum[i >> 8];
    if (i == NN) row_start[NN] = EE + NN;
}
// scatter edges (and self loops) into dst-sorted src list
__global__ void scatter_kernel(const int* __restrict__ ei, const int* __restrict__ row_start,
                               int* __restrict__ fill, int* __restrict__ sorted) {
    int t = blockIdx.x * 256 + threadIdx.x;
    if (t >= EE + NN) return;
    int s, d;
    if (t < EE) { s = ei[t]; d = ei[EE + t]; }
    else        { s = t - EE; d = s; }
    int pos = atomicAdd(&fill[d], 1);
    sorted[row_start[d] + pos] = s;
}

// ================= tiled fp32 GEMM: C[N x K] = A[N x M] @ B[M x K] =================
__global__ __launch_bounds__(256) void gemm_tiled(
        const float* __restrict__ A, const float* __restrict__ B,
        float* __restrict__ C, int M, int K) {
    __shared__ float As[16][64];
    __shared__ float Bs[16][64];
    int t = threadIdx.x;
    int rowBase = blockIdx.y * 64;
    int colBase = blockIdx.x * 64;
    int ty = t >> 4, tx = t & 15;
    float acc[4][4] = {};
    int arow = t >> 2;
    int ak4 = (t & 3) * 4;
    int bkk = t >> 4;
    int bc4 = (t & 15) * 4;
    for (int k0 = 0; k0 < M; k0 += 16) {
        float4 av = make_float4(0.f, 0.f, 0.f, 0.f);
        int gr = rowBase + arow;
        if (gr < NN) av = *(const float4*)&A[(long)gr * M + k0 + ak4];
        As[ak4 + 0][arow] = av.x;
        As[ak4 + 1][arow] = av.y;
        As[ak4 + 2][arow] = av.z;
        As[ak4 + 3][arow] = av.w;
        float4 bv = *(const float4*)&B[(long)(k0 + bkk) * K + colBase + bc4];
        *(float4*)&Bs[bkk][bc4] = bv;
        __syncthreads();
#pragma unroll
        for (int kk = 0; kk < 16; ++kk) {
            float a0 = As[kk][ty * 4 + 0], a1 = As[kk][ty * 4 + 1];
            float a2 = As[kk][ty * 4 + 2], a3 = As[kk][ty * 4 + 3];
            float b0 = Bs[kk][tx * 4 + 0], b1 = Bs[kk][tx * 4 + 1];
            float b2 = Bs[kk][tx * 4 + 2], b3 = Bs[kk][tx * 4 + 3];
            acc[0][0] += a0 * b0; acc[0][1] += a0 * b1; acc[0][2] += a0 * b2; acc[0][3] += a0 * b3;
            acc[1][0] += a1 * b0; acc[1][1] += a1 * b1; acc[1][2] += a1 * b2; acc[1][3] += a1 * b3;
            acc[2][0] += a2 * b0; acc[2][1] += a2 * b1; acc[2][2] += a2 * b2; acc[2][3] += a2 * b3;
            acc[3][0] += a3 * b0; acc[3][1] += a3 * b1; acc[3][2] += a3 * b2; acc[3][3] += a3 * b3;
        }
        __syncthreads();
    }
#pragma unroll
    for (int j = 0; j < 4; ++j) {
        int gr = rowBase + ty * 4 + j;
        if (gr < NN) {
            float4 o = make_float4(acc[j][0], acc[j][1], acc[j][2], acc[j][3]);
            *(float4*)&C[(long)gr * K + colBase + tx * 4] = o;
        }
    }
}

// ================= GCN gather (dst-centric, no atomics) =================
__global__ __launch_bounds__(256) void gcn_gather(
        const int* __restrict__ row_start, const int* __restrict__ sorted,
        const float* __restrict__ dinv, const float* __restrict__ h0,
        float* __restrict__ agg) {
    int node = blockIdx.x * 4 + (threadIdx.x >> 6);
    if (node >= NN) return;
    int c = threadIdx.x & 63;
    int b = row_start[node], e = row_start[node + 1];
    float acc = 0.f;
    for (int i = b; i < e; ++i) {
        int s = sorted[i];                      // wave-broadcast load
        acc += h0[(long)s * 64 + c] * dinv[s];
    }
    agg[(long)node * 64 + c] = acc * dinv[node];
}

// ================= BatchNorm =================
__global__ void bn_stats(const float* __restrict__ x, const float* __restrict__ bias,
                         float* __restrict__ sums, float* __restrict__ sumsq,
                         int C, int relu_mode) {
    int col = threadIdx.x & (C - 1);
    int sub = threadIdx.x / C;
    int stride = 256 / C;
    int r0 = blockIdx.x * 256;
    int r1 = min(r0 + 256, NN);
    float b = bias[col];
    float s = 0.f, ss = 0.f;
    for (int r = r0 + sub; r < r1; r += stride) {
        float v = x[(long)r * C + col] + b;
        if (relu_mode) v = fmaxf(v, 0.f);
        s += v; ss += v * v;
    }
    atomicAdd(&sums[col], s);
    atomicAdd(&sumsq[col], ss);
}
__global__ void bn_finalize(const float* __restrict__ sums, const float* __restrict__ sumsq,
                            const float* __restrict__ g, const float* __restrict__ beta,
                            float* __restrict__ scale, float* __restrict__ shift, int C) {
    int c = threadIdx.x;
    if (c < C) {
        float mean = sums[c] / (float)NN;
        float var = sumsq[c] / (float)NN - mean * mean;
        float sc = g[c] * rsqrtf(var + BN_EPS);
        scale[c] = sc;
        shift[c] = beta[c] - mean * sc;
    }
}
__global__ void bn_apply(float* __restrict__ x, const float* __restrict__ bias,
                         const float* __restrict__ scale, const float* __restrict__ shift,
                         int C, int mode) {
    long total = (long)NN * C;
    long idx = (long)blockIdx.x * 256 + threadIdx.x;
    if (idx < total) {
        int c = (int)(idx & (C - 1));
        float v = x[idx] + bias[c];
        if (mode == 0) v = fmaxf(v, 0.f);
        v = scale[c] * v + shift[c];
        if (mode == 1) v = (v > 0.f) ? v : expm1f(v);
        x[idx] = v;
    }
}

// ================= GAT =================
// per-node per-head dot products: alpha_s/alpha_d [N,4]
__global__ void gat_alpha(const float* __restrict__ h, const float* __restrict__ a_src,
                          const float* __restrict__ a_dst,
                          float* __restrict__ alpha_s, float* __restrict__ alpha_d) {
    int n = blockIdx.x;
    int t = threadIdx.x;
    float hv = h[(long)n * 256 + t];
    float vs = hv * a_src[t];
    float vd = hv * a_dst[t];
    for (int off = 32; off > 0; off >>= 1) {
        vs += __shfl_down(vs, off);
        vd += __shfl_down(vd, off);
    }
    if ((t & 63) == 0) {
        int head = t >> 6;
        alpha_s[n * 4 + head] = vs;
        alpha_d[n * 4 + head] = vd;
    }
}

// fused per-dst softmax + weighted aggregation. One block (256 thr) per node.
__global__ __launch_bounds__(256) void gat_fused(
        const int* __restrict__ row_start, const int* __restrict__ sorted,
        const float* __restrict__ as, const float* __restrict__ ad,
        const float* __restrict__ h, float* __restrict__ out) {
    __shared__ float red[256];
    __shared__ float hmax[4];
    __shared__ float hsum[4];
    __shared__ float watt[MAXD][4];
    int n = blockIdx.x;
    int t = threadIdx.x;
    int b = row_start[n], e = row_start[n + 1];
    int hh = t & 3;
    float adn = ad[n * 4 + hh];
    // pass A: per-head max of leakyrelu(as[s]+ad[n])
    float lm = -1e30f;
    for (int i = b + (t >> 2); i < e; i += 64) {
        int s = sorted[i];
        float ev = as[s * 4 + hh] + adn;
        ev = (ev > 0.f) ? ev : NEG_SLOPE * ev;
        lm = fmaxf(lm, ev);
    }
    red[t] = lm;
    __syncthreads();
    for (int off = 128; off >= 4; off >>= 1) {
        if (t < off) red[t] = fmaxf(red[t], red[t + off]);
        __syncthreads();
    }
    if (t < 4) hmax[t] = red[t];
    __syncthreads();
    // pass B: per-head sum of exp(ev - max); cache w in LDS (k < MAXD)
    float m = hmax[hh];
    float ls = 0.f;
    for (int i = b + (t >> 2); i < e; i += 64) {
        int s = sorted[i];
        float ev = as[s * 4 + hh] + adn;
        ev = (ev > 0.f) ? ev : NEG_SLOPE * ev;
        float w = __expf(ev - m);
        int k = i - b;
        if (k < MAXD) watt[k][hh] = w;
        ls += w;
    }
    __syncthreads();            // watt writes + red reuse
    red[t] = ls;
    __syncthreads();
    for (int off = 128; off >= 4; off >>= 1) {
        if (t < off) red[t] += red[t + off];
        __syncthreads();
    }
    if (t < 4) hsum[t] = red[t];
    __syncthreads();
    // pass C: weighted gather, one column per thread
    int head = t >> 6;
    float m2 = hmax[head];
    float inv = 1.0f / hsum[head];
    float adn2 = ad[n * 4 + head];
    float acc = 0.f;
    for (int i = b; i < e; ++i) {
        int s = sorted[i];                      // wave-broadcast load
        int k = i - b;
        float w;
        if (k < MAXD) w = watt[k][head];        // LDS broadcast
        else {
            float ev = as[s * 4 + head] + adn2;
            ev = (ev > 0.f) ? ev : NEG_SLOPE * ev;
            w = __expf(ev - m2);
        }
        acc += w * h[(long)s * 256 + t];
    }
    out[(long)n * 256 + t] = acc * inv;
}

// ================= launch =================
extern "C" void kernel_launch(void* const* d_in, const int* in_sizes, int n_in,
                              void* d_out, int out_size, void* d_ws, size_t ws_size,
                              hipStream_t stream) {
    const float* x      = (const float*)d_in[0];
    const int*   ei     = (const int*)d_in[1];
    const float* W_gcn  = (const float*)d_in[2];
    const float* b_gcn  = (const float*)d_in[3];
    const float* g0     = (const float*)d_in[4];
    const float* beta0  = (const float*)d_in[5];
    const float* W1     = (const float*)d_in[6];
    const float* a_src1 = (const float*)d_in[7];
    const float* a_dst1 = (const float*)d_in[8];
    const float* b1     = (const float*)d_in[9];
    const float* g1     = (const float*)d_in[10];
    const float* beta1  = (const float*)d_in[11];
    const float* W2     = (const float*)d_in[12];
    const float* a_src2 = (const float*)d_in[13];
    const float* a_dst2 = (const float*)d_in[14];
    const float* b2     = (const float*)d_in[15];
    const float* g2     = (const float*)d_in[16];
    const float* beta2  = (const float*)d_in[17];

    const long N = NN;
    float* ws = (float*)d_ws;

    // ---- layout (641N floats total, same footprint as round 1) ----
    float* dinv    = ws;                       // N
    // overlay region ws+N .. ws+65N (alpha + bn scalars + CSR ints):
    float* alpha_s = ws + N;                   // 4N
    float* alpha_d = alpha_s + 4 * N;          // 4N
    float* sums    = alpha_d + 4 * N;          // 256
    float* sumsq   = sums + 256;               // 256
    float* scale   = sumsq + 256;              // 256
    float* shift   = scale + 256;              // 256
    int*   row_start = (int*)(shift + 256);    // N+1
    int*   fill      = row_start + NN + 1;     // N
    int*   deg_i     = fill + NN;              // N  (contiguous with fill for one memset)
    int*   sorted    = deg_i + NN;             // E+N
    int*   bsum      = sorted + EE + NN;       // 391
    float* agg0 = ws + 65 * N;                 // 64N  -> x1
    float* h1   = ws + 129 * N;                // 256N (h1, then h2)
    float* acc1 = ws + 385 * N;                // 256N (x2)
    float* h0   = acc1;                        // alias: h0 [N,64] dead before acc1 live

    const int BLK = 256;
    dim3 blk(BLK);
    const int NBLK_N = (NN + 255) / 256;       // 391

    // ===== CSR build (by dst, self-loops included) =====
    hipMemsetAsync(fill, 0, 2L * NN * sizeof(int), stream);   // fill + deg_i
    hist_kernel<<<(EE + 255) / 256, blk, 0, stream>>>(ei, deg_i);
    dinv_kernel<<<NBLK_N, blk, 0, stream>>>(deg_i, dinv);
    scan_k1<<<NBLK_N, blk, 0, stream>>>(deg_i, row_start, bsum);
    scan_k2<<<1, 512, 0, stream>>>(bsum, NBLK_N);
    scan_k3<<<(NN + 1 + 255) / 256, blk, 0, stream>>>(row_start, bsum);
    scatter_kernel<<<(EE + NN + 255) / 256, blk, 0, stream>>>(ei, row_start, fill, sorted);

    // ===== GCN =====
    gemm_tiled<<<dim3(CH / 64, (NN + 63) / 64), blk, 0, stream>>>(x, W_gcn, h0, FIN, CH);
    gcn_gather<<<(NN + 3) / 4, blk, 0, stream>>>(row_start, sorted, dinv, h0, agg0);
    hipMemsetAsync(sums, 0, 512 * sizeof(float), stream);
    bn_stats<<<NBLK_N, blk, 0, stream>>>(agg0, b_gcn, sums, sumsq, CH, 1);
    bn_finalize<<<1, CH, 0, stream>>>(sums, sumsq, g0, beta0, scale, shift, CH);
    bn_apply<<<(NN * CH) / BLK, blk, 0, stream>>>(agg0, b_gcn, scale, shift, CH, 0);
    // agg0 is now x1 [N,64]

    // ===== GAT layer 1 =====
    gemm_tiled<<<dim3(C1 / 64, (NN + 63) / 64), blk, 0, stream>>>(agg0, W1, h1, CH, C1);
    gat_alpha<<<NN, blk, 0, stream>>>(h1, a_src1, a_dst1, alpha_s, alpha_d);
    gat_fused<<<NN, blk, 0, stream>>>(row_start, sorted, alpha_s, alpha_d, h1, acc1);
    hipMemsetAsync(sums, 0, 512 * sizeof(float), stream);
    bn_stats<<<NBLK_N, blk, 0, stream>>>(acc1, b1, sums, sumsq, C1, 0);
    bn_finalize<<<1, C1, 0, stream>>>(sums, sumsq, g1, beta1, scale, shift, C1);
    bn_apply<<<(NN * C1) / BLK, blk, 0, stream>>>(acc1, b1, scale, shift, C1, 1);
    // acc1 is now x2 [N,256]

    // ===== GAT layer 2 =====
    gemm_tiled<<<dim3(C1 / 64, (NN + 63) / 64), blk, 0, stream>>>(acc1, W2, h1, C1, C1);
    gat_alpha<<<NN, blk, 0, stream>>>(h1, a_src2, a_dst2, alpha_s, alpha_d);
    gat_fused<<<NN, blk, 0, stream>>>(row_start, sorted, alpha_s, alpha_d, h1, (float*)d_out);
    hipMemsetAsync(sums, 0, 512 * sizeof(float), stream);
    bn_stats<<<NBLK_N, blk, 0, stream>>>((float*)d_out, b2, sums, sumsq, C1, 0);
    bn_finalize<<<1, C1, 0, stream>>>(sums, sumsq, g2, beta2, scale, shift, C1);
    bn_apply<<<(NN * C1) / BLK, blk, 0, stream>>>((float*)d_out, b2, scale, shift, C1, 1);
}

// Round 3
// 1356.867 us; speedup vs baseline: 2.0478x; 1.2480x over previous
//
#include <hip/hip_runtime.h>
#include <hip/hip_bf16.h>
#include <math.h>

#define NN 100000
#define EE 800000
#define FIN 256
#define CH 64      // HID
#define C1 256     // H*HID
#define BN_EPS 1e-5f
#define NEG_SLOPE 0.2f
#define MAXD 64    // LDS cache depth for per-edge attention weights

typedef __attribute__((ext_vector_type(8))) short short8;
typedef __attribute__((ext_vector_type(4))) float f32x4;

__device__ __forceinline__ float bf2f(ushort u) {
    return __uint_as_float(((unsigned)u) << 16);
}
__device__ __forceinline__ ushort f2bf(float f) {
    unsigned u = __float_as_uint(f);
    return (ushort)((u + 0x7FFF + ((u >> 16) & 1)) >> 16);   // RNE
}

// ================= CSR build =================
__global__ void hist_kernel(const int* __restrict__ ei, int* __restrict__ deg) {
    int t = blockIdx.x * 256 + threadIdx.x;
    if (t < EE) atomicAdd(&deg[ei[EE + t]], 1);
}
__global__ void dinv_kernel(const int* __restrict__ deg, float* __restrict__ dinv) {
    int i = blockIdx.x * 256 + threadIdx.x;
    if (i < NN) dinv[i] = rsqrtf((float)(deg[i] + 1));  // +1 self loop
}
__global__ void scan_k1(const int* __restrict__ deg, int* __restrict__ row_start,
                        int* __restrict__ bsum) {
    __shared__ int sh[256];
    int t = threadIdx.x;
    int i = blockIdx.x * 256 + t;
    int v = (i < NN) ? (deg[i] + 1) : 0;
    sh[t] = v;
    __syncthreads();
    for (int off = 1; off < 256; off <<= 1) {
        int add = (t >= off) ? sh[t - off] : 0;
        __syncthreads();
        sh[t] += add;
        __syncthreads();
    }
    if (i < NN) row_start[i] = sh[t] - v;
    if (t == 255) bsum[blockIdx.x] = sh[255];
}
__global__ void scan_k2(int* __restrict__ bsum, int nb) {
    __shared__ int sh[512];
    int t = threadIdx.x;
    int v = (t < nb) ? bsum[t] : 0;
    sh[t] = v;
    __syncthreads();
    for (int off = 1; off < 512; off <<= 1) {
        int add = (t >= off) ? sh[t - off] : 0;
        __syncthreads();
        sh[t] += add;
        __syncthreads();
    }
    if (t < nb) bsum[t] = sh[t] - v;
}
__global__ void scan_k3(int* __restrict__ row_start, const int* __restrict__ bsum) {
    int i = blockIdx.x * 256 + threadIdx.x;
    if (i < NN) row_start[i] += bsum[i >> 8];
    if (i == NN) row_start[NN] = EE + NN;
}
__global__ void scatter_kernel(const int* __restrict__ ei, const int* __restrict__ row_start,
                               int* __restrict__ fill, int* __restrict__ sorted) {
    int t = blockIdx.x * 256 + threadIdx.x;
    if (t >= EE + NN) return;
    int s, d;
    if (t < EE) { s = ei[t]; d = ei[EE + t]; }
    else        { s = t - EE; d = s; }
    int pos = atomicAdd(&fill[d], 1);
    sorted[row_start[d] + pos] = s;
}

// ================= conversions =================
__global__ void convert_f32_bf16(const float* __restrict__ in, ushort* __restrict__ out, long n4) {
    long i = (long)blockIdx.x * 256 + threadIdx.x;
    if (i < n4) {
        float4 v = *(const float4*)&in[i * 4];
        ushort4 o;
        o.x = f2bf(v.x); o.y = f2bf(v.y); o.z = f2bf(v.z); o.w = f2bf(v.w);
        *(ushort4*)&out[i * 4] = o;
    }
}
// Bt[n][m] = bf16(W[m][n]); W is [M,K], Bt is [K,M]
__global__ void transpose_w(const float* __restrict__ W, ushort* __restrict__ Bt, int M, int K) {
    int idx = blockIdx.x * 256 + threadIdx.x;
    if (idx < M * K) {
        int m = idx / K, n = idx % K;
        Bt[n * M + m] = f2bf(W[idx]);
    }
}

// ================= bf16 MFMA GEMM =================
// C[N x K] = A[N x M] @ B[M x K]; A bf16 row-major, Bt bf16 [K][M], C bf16.
// grid(K/64, ceil(N/64)), block 256 (4 waves); 64x64 tile, wave w does rows w*16..w*16+15.
__global__ __launch_bounds__(256) void gemm_mfma(
        const ushort* __restrict__ A, const ushort* __restrict__ Bt,
        ushort* __restrict__ C, int M, int K) {
    __shared__ ushort As[64][40];   // row stride 80B (16B-aligned), breaks pow2 banks
    __shared__ ushort Bs[64][40];
    int t = threadIdx.x;
    int w = t >> 6;
    int l = t & 63;
    int rowBase = blockIdx.y * 64;
    int colBase = blockIdx.x * 64;
    int srow = t >> 2;            // 0..63
    int sk = (t & 3) * 8;         // 0,8,16,24
    int m = l & 15, q = l >> 4;
    f32x4 acc[4] = {};
    for (int k0 = 0; k0 < M; k0 += 32) {
        uint4 av = make_uint4(0u, 0u, 0u, 0u);
        int gr = rowBase + srow;
        if (gr < NN) av = *(const uint4*)&A[(long)gr * M + k0 + sk];
        uint4 bv = *(const uint4*)&Bt[(long)(colBase + srow) * M + k0 + sk];
        *(uint4*)&As[srow][sk] = av;
        *(uint4*)&Bs[srow][sk] = bv;
        __syncthreads();
        short8 af = *(const short8*)&As[w * 16 + m][q * 8];
#pragma unroll
        for (int c = 0; c < 4; ++c) {
            short8 bf = *(const short8*)&Bs[c * 16 + m][q * 8];
            acc[c] = __builtin_amdgcn_mfma_f32_16x16x32_bf16(af, bf, acc[c], 0, 0, 0);
        }
        __syncthreads();
    }
    // C/D: col = lane&15, row = (lane>>4)*4 + reg
#pragma unroll
    for (int c = 0; c < 4; ++c) {
#pragma unroll
        for (int r = 0; r < 4; ++r) {
            int orow = rowBase + w * 16 + q * 4 + r;
            if (orow < NN) C[(long)orow * K + colBase + c * 16 + m] = f2bf(acc[c][r]);
        }
    }
}

// ================= GCN gather (bf16 h, dst-centric) =================
__global__ __launch_bounds__(256) void gcn_gather(
        const int* __restrict__ row_start, const int* __restrict__ sorted,
        const float* __restrict__ dinv, const ushort* __restrict__ h0,
        float* __restrict__ agg) {
    int node = blockIdx.x * 4 + (threadIdx.x >> 6);
    if (node >= NN) return;
    int c = threadIdx.x & 63;
    int b = row_start[node], e = row_start[node + 1];
    float acc = 0.f, acc2 = 0.f;
    int i = b;
    for (; i + 1 < e; i += 2) {
        int s0 = sorted[i], s1 = sorted[i + 1];
        float v0 = bf2f(h0[(long)s0 * 64 + c]);
        float v1 = bf2f(h0[(long)s1 * 64 + c]);
        acc += v0 * dinv[s0];
        acc2 += v1 * dinv[s1];
    }
    if (i < e) {
        int s0 = sorted[i];
        acc += bf2f(h0[(long)s0 * 64 + c]) * dinv[s0];
    }
    agg[(long)node * 64 + c] = (acc + acc2) * dinv[node];
}

// ================= BatchNorm =================
__global__ void bn_stats(const float* __restrict__ x, const float* __restrict__ bias,
                         float* __restrict__ sums, float* __restrict__ sumsq,
                         int C, int relu_mode) {
    int col = threadIdx.x & (C - 1);
    int sub = threadIdx.x / C;
    int stride = 256 / C;
    int r0 = blockIdx.x * 256;
    int r1 = min(r0 + 256, NN);
    float b = bias[col];
    float s = 0.f, ss = 0.f;
    for (int r = r0 + sub; r < r1; r += stride) {
        float v = x[(long)r * C + col] + b;
        if (relu_mode) v = fmaxf(v, 0.f);
        s += v; ss += v * v;
    }
    atomicAdd(&sums[col], s);
    atomicAdd(&sumsq[col], ss);
}
__global__ void bn_finalize(const float* __restrict__ sums, const float* __restrict__ sumsq,
                            const float* __restrict__ g, const float* __restrict__ beta,
                            float* __restrict__ scale, float* __restrict__ shift, int C) {
    int c = threadIdx.x;
    if (c < C) {
        float mean = sums[c] / (float)NN;
        float var = sumsq[c] / (float)NN - mean * mean;
        float sc = g[c] * rsqrtf(var + BN_EPS);
        scale[c] = sc;
        shift[c] = beta[c] - mean * sc;
    }
}
// mode 0: relu(x+b) pre-BN, no post. mode 1: (x+b) pre-BN, ELU post.
// out_bf16: write ushort bf16, else float.
__global__ void bn_apply(const float* __restrict__ x, const float* __restrict__ bias,
                         const float* __restrict__ scale, const float* __restrict__ shift,
                         int C, int mode, void* __restrict__ out, int out_bf16) {
    long total = (long)NN * C;
    long idx = (long)blockIdx.x * 256 + threadIdx.x;
    if (idx < total) {
        int c = (int)(idx & (C - 1));
        float v = x[idx] + bias[c];
        if (mode == 0) v = fmaxf(v, 0.f);
        v = scale[c] * v + shift[c];
        if (mode == 1) v = (v > 0.f) ? v : expm1f(v);
        if (out_bf16) ((ushort*)out)[idx] = f2bf(v);
        else ((float*)out)[idx] = v;
    }
}

// ================= GAT =================
__global__ void gat_alpha(const ushort* __restrict__ h, const float* __restrict__ a_src,
                          const float* __restrict__ a_dst,
                          float* __restrict__ alpha_s, float* __restrict__ alpha_d) {
    int n = blockIdx.x;
    int t = threadIdx.x;
    float hv = bf2f(h[(long)n * 256 + t]);
    float vs = hv * a_src[t];
    float vd = hv * a_dst[t];
    for (int off = 32; off > 0; off >>= 1) {
        vs += __shfl_down(vs, off);
        vd += __shfl_down(vd, off);
    }
    if ((t & 63) == 0) {
        int head = t >> 6;
        alpha_s[n * 4 + head] = vs;
        alpha_d[n * 4 + head] = vd;
    }
}

// fused per-dst softmax + weighted bf16 gather. One block (256 thr) per node.
__global__ __launch_bounds__(256) void gat_fused(
        const int* __restrict__ row_start, const int* __restrict__ sorted,
        const float* __restrict__ as, const float* __restrict__ ad,
        const ushort* __restrict__ h, float* __restrict__ out) {
    __shared__ float red[256];
    __shared__ float hmax[4];
    __shared__ float hsum[4];
    __shared__ float watt[MAXD][4];
    int n = blockIdx.x;
    int t = threadIdx.x;
    int b = row_start[n], e = row_start[n + 1];
    int hh = t & 3;
    float adn = ad[n * 4 + hh];
    // pass A: per-head max
    float lm = -1e30f;
    for (int i = b + (t >> 2); i < e; i += 64) {
        int s = sorted[i];
        float ev = as[s * 4 + hh] + adn;
        ev = (ev > 0.f) ? ev : NEG_SLOPE * ev;
        lm = fmaxf(lm, ev);
    }
    red[t] = lm;
    __syncthreads();
    for (int off = 128; off >= 4; off >>= 1) {
        if (t < off) red[t] = fmaxf(red[t], red[t + off]);
        __syncthreads();
    }
    if (t < 4) hmax[t] = red[t];
    __syncthreads();
    // pass B: per-head sum of exp; cache w in LDS
    float mh = hmax[hh];
    float ls = 0.f;
    for (int i = b + (t >> 2); i < e; i += 64) {
        int s = sorted[i];
        float ev = as[s * 4 + hh] + adn;
        ev = (ev > 0.f) ? ev : NEG_SLOPE * ev;
        float wv = __expf(ev - mh);
        int k = i - b;
        if (k < MAXD) watt[k][hh] = wv;
        ls += wv;
    }
    __syncthreads();
    red[t] = ls;
    __syncthreads();
    for (int off = 128; off >= 4; off >>= 1) {
        if (t < off) red[t] += red[t + off];
        __syncthreads();
    }
    if (t < 4) hsum[t] = red[t];
    __syncthreads();
    // pass C: weighted gather, one column per thread, 2-way unrolled
    int head = t >> 6;
    float m2 = hmax[head];
    float inv = 1.0f / hsum[head];
    float adn2 = ad[n * 4 + head];
    float acc = 0.f, acc2 = 0.f;
    int i = b;
    for (; i + 1 < e; i += 2) {
        int s0 = sorted[i], s1 = sorted[i + 1];
        int k0 = i - b;
        float w0, w1;
        if (k0 + 1 < MAXD) { w0 = watt[k0][head]; w1 = watt[k0 + 1][head]; }
        else {
            float e0 = as[s0 * 4 + head] + adn2;
            e0 = (e0 > 0.f) ? e0 : NEG_SLOPE * e0;
            w0 = __expf(e0 - m2);
            float e1 = as[s1 * 4 + head] + adn2;
            e1 = (e1 > 0.f) ? e1 : NEG_SLOPE * e1;
            w1 = __expf(e1 - m2);
        }
        float v0 = bf2f(h[(long)s0 * 256 + t]);
        float v1 = bf2f(h[(long)s1 * 256 + t]);
        acc += w0 * v0;
        acc2 += w1 * v1;
    }
    if (i < e) {
        int s0 = sorted[i];
        int k0 = i - b;
        float w0;
        if (k0 < MAXD) w0 = watt[k0][head];
        else {
            float e0 = as[s0 * 4 + head] + adn2;
            e0 = (e0 > 0.f) ? e0 : NEG_SLOPE * e0;
            w0 = __expf(e0 - m2);
        }
        acc += w0 * bf2f(h[(long)s0 * 256 + t]);
    }
    out[(long)n * 256 + t] = (acc + acc2) * inv;
}

// ================= launch =================
extern "C" void kernel_launch(void* const* d_in, const int* in_sizes, int n_in,
                              void* d_out, int out_size, void* d_ws, size_t ws_size,
                              hipStream_t stream) {
    const float* x      = (const float*)d_in[0];
    const int*   ei     = (const int*)d_in[1];
    const float* W_gcn  = (const float*)d_in[2];
    const float* b_gcn  = (const float*)d_in[3];
    const float* g0     = (const float*)d_in[4];
    const float* beta0  = (const float*)d_in[5];
    const float* W1     = (const float*)d_in[6];
    const float* a_src1 = (const float*)d_in[7];
    const float* a_dst1 = (const float*)d_in[8];
    const float* b1     = (const float*)d_in[9];
    const float* g1     = (const float*)d_in[10];
    const float* beta1  = (const float*)d_in[11];
    const float* W2     = (const float*)d_in[12];
    const float* a_src2 = (const float*)d_in[13];
    const float* a_dst2 = (const float*)d_in[14];
    const float* b2     = (const float*)d_in[15];
    const float* g2     = (const float*)d_in[16];
    const float* beta2  = (const float*)d_in[17];

    const long N = NN;
    float* ws = (float*)d_ws;

    // ---- layout (631N floats ~ 252 MB) ----
    float* dinv    = ws;                        // N
    float* alpha_s = ws + N;                    // 4N
    float* alpha_d = ws + 5 * N;                // 4N
    float* sums    = ws + 9 * N;                // 256
    float* sumsq   = sums + 256;
    float* scale   = sumsq + 256;
    float* shift   = scale + 256;
    int*   row_start = (int*)(shift + 256);     // N+1
    int*   fill      = row_start + NN + 1;      // N
    int*   deg_i     = fill + NN;               // N
    int*   sorted    = deg_i + NN;              // 9N
    int*   bsum      = sorted + EE + NN;        // ~400
    ushort* Wgt  = (ushort*)(ws + 22 * N);      // 64x256
    ushort* W1t  = Wgt + 16384;                 // 256x64
    ushort* W2t  = W1t + 16384;                 // 256x256
    ushort* h0b  = (ushort*)(ws + 23 * N);      // [N,64] bf16 (32N slots); reused as x1b
    ushort* x1b  = h0b;
    float*  agg0 = ws + 55 * N;                 // [N,64] fp32 (64N)
    ushort* h1b  = (ushort*)(ws + 119 * N);     // [N,256] bf16 (128N); reused as h2b
    ushort* x2b  = (ushort*)(ws + 247 * N);     // [N,256] bf16 (128N)
    float*  acc1 = ws + 375 * N;                // [N,256] fp32 (256N)
    ushort* xb   = (ushort*)acc1;               // overlay: x bf16 (128N), dead before acc1 live
    float*  outp = (float*)d_out;

    const int BLK = 256;
    dim3 blk(BLK);
    const int NBLK_N = (NN + 255) / 256;        // 391

    // ===== CSR build =====
    hipMemsetAsync(fill, 0, 2L * NN * sizeof(int), stream);
    hist_kernel<<<(EE + 255) / 256, blk, 0, stream>>>(ei, deg_i);
    dinv_kernel<<<NBLK_N, blk, 0, stream>>>(deg_i, dinv);
    scan_k1<<<NBLK_N, blk, 0, stream>>>(deg_i, row_start, bsum);
    scan_k2<<<1, 512, 0, stream>>>(bsum, NBLK_N);
    scan_k3<<<(NN + 1 + 255) / 256, blk, 0, stream>>>(row_start, bsum);
    scatter_kernel<<<(EE + NN + 255) / 256, blk, 0, stream>>>(ei, row_start, fill, sorted);

    // ===== conversions =====
    convert_f32_bf16<<<(int)((N * 256 / 4 + 255) / 256), blk, 0, stream>>>(x, xb, N * 256 / 4);
    transpose_w<<<(FIN * CH + 255) / 256, blk, 0, stream>>>(W_gcn, Wgt, FIN, CH);
    transpose_w<<<(CH * C1 + 255) / 256, blk, 0, stream>>>(W1, W1t, CH, C1);
    transpose_w<<<(C1 * C1 + 255) / 256, blk, 0, stream>>>(W2, W2t, C1, C1);

    // ===== GCN =====
    gemm_mfma<<<dim3(CH / 64, (NN + 63) / 64), blk, 0, stream>>>(xb, Wgt, h0b, FIN, CH);
    gcn_gather<<<(NN + 3) / 4, blk, 0, stream>>>(row_start, sorted, dinv, h0b, agg0);
    hipMemsetAsync(sums, 0, 512 * sizeof(float), stream);
    bn_stats<<<NBLK_N, blk, 0, stream>>>(agg0, b_gcn, sums, sumsq, CH, 1);
    bn_finalize<<<1, CH, 0, stream>>>(sums, sumsq, g0, beta0, scale, shift, CH);
    bn_apply<<<(int)(N * CH / BLK), blk, 0, stream>>>(agg0, b_gcn, scale, shift, CH, 0, x1b, 1);

    // ===== GAT layer 1 =====
    gemm_mfma<<<dim3(C1 / 64, (NN + 63) / 64), blk, 0, stream>>>(x1b, W1t, h1b, CH, C1);
    gat_alpha<<<NN, blk, 0, stream>>>(h1b, a_src1, a_dst1, alpha_s, alpha_d);
    gat_fused<<<NN, blk, 0, stream>>>(row_start, sorted, alpha_s, alpha_d, h1b, acc1);
    hipMemsetAsync(sums, 0, 512 * sizeof(float), stream);
    bn_stats<<<NBLK_N, blk, 0, stream>>>(acc1, b1, sums, sumsq, C1, 0);
    bn_finalize<<<1, C1, 0, stream>>>(sums, sumsq, g1, beta1, scale, shift, C1);
    bn_apply<<<(int)(N * C1 / BLK), blk, 0, stream>>>(acc1, b1, scale, shift, C1, 1, x2b, 1);

    // ===== GAT layer 2 =====
    gemm_mfma<<<dim3(C1 / 64, (NN + 63) / 64), blk, 0, stream>>>(x2b, W2t, h1b, C1, C1);
    gat_alpha<<<NN, blk, 0, stream>>>(h1b, a_src2, a_dst2, alpha_s, alpha_d);
    gat_fused<<<NN, blk, 0, stream>>>(row_start, sorted, alpha_s, alpha_d, h1b, outp);
    hipMemsetAsync(sums, 0, 512 * sizeof(float), stream);
    bn_stats<<<NBLK_N, blk, 0, stream>>>(outp, b2, sums, sumsq, C1, 0);
    bn_finalize<<<1, C1, 0, stream>>>(sums, sumsq, g2, beta2, scale, shift, C1);
    bn_apply<<<(int)(N * C1 / BLK), blk, 0, stream>>>(outp, b2, scale, shift, C1, 1, outp, 0);
}

// Round 5
// 1131.247 us; speedup vs baseline: 2.4562x; 1.1994x over previous
//
#include <hip/hip_runtime.h>
#include <hip/hip_bf16.h>
#include <math.h>

#define NN 100000
#define EE 800000
#define FIN 256
#define CH 64      // HID
#define C1 256     // H*HID
#define BN_EPS 1e-5f
#define NEG_SLOPE 0.2f

typedef __attribute__((ext_vector_type(8))) short short8;
typedef __attribute__((ext_vector_type(4))) float f32x4;

__device__ __forceinline__ float bf2f(ushort u) {
    return __uint_as_float(((unsigned)u) << 16);
}
__device__ __forceinline__ ushort f2bf(float f) {
    unsigned u = __float_as_uint(f);
    return (ushort)((u + 0x7FFF + ((u >> 16) & 1)) >> 16);   // RNE
}

// ================= CSR build =================
__global__ void hist_kernel(const int* __restrict__ ei, int* __restrict__ deg) {
    int t = blockIdx.x * 256 + threadIdx.x;
    if (t < EE) atomicAdd(&deg[ei[EE + t]], 1);
}
__global__ void dinv_kernel(const int* __restrict__ deg, float* __restrict__ dinv) {
    int i = blockIdx.x * 256 + threadIdx.x;
    if (i < NN) dinv[i] = rsqrtf((float)(deg[i] + 1));  // +1 self loop
}
__global__ void scan_k1(const int* __restrict__ deg, int* __restrict__ row_start,
                        int* __restrict__ bsum) {
    __shared__ int sh[256];
    int t = threadIdx.x;
    int i = blockIdx.x * 256 + t;
    int v = (i < NN) ? (deg[i] + 1) : 0;
    sh[t] = v;
    __syncthreads();
    for (int off = 1; off < 256; off <<= 1) {
        int add = (t >= off) ? sh[t - off] : 0;
        __syncthreads();
        sh[t] += add;
        __syncthreads();
    }
    if (i < NN) row_start[i] = sh[t] - v;
    if (t == 255) bsum[blockIdx.x] = sh[255];
}
__global__ void scan_k2(int* __restrict__ bsum, int nb) {
    __shared__ int sh[512];
    int t = threadIdx.x;
    int v = (t < nb) ? bsum[t] : 0;
    sh[t] = v;
    __syncthreads();
    for (int off = 1; off < 512; off <<= 1) {
        int add = (t >= off) ? sh[t - off] : 0;
        __syncthreads();
        sh[t] += add;
        __syncthreads();
    }
    if (t < nb) bsum[t] = sh[t] - v;
}
__global__ void scan_k3(int* __restrict__ row_start, const int* __restrict__ bsum) {
    int i = blockIdx.x * 256 + threadIdx.x;
    if (i < NN) row_start[i] += bsum[i >> 8];
    if (i == NN) row_start[NN] = EE + NN;
}
__global__ void scatter_kernel(const int* __restrict__ ei, const int* __restrict__ row_start,
                               int* __restrict__ fill, int* __restrict__ sorted) {
    int t = blockIdx.x * 256 + threadIdx.x;
    if (t >= EE + NN) return;
    int s, d;
    if (t < EE) { s = ei[t]; d = ei[EE + t]; }
    else        { s = t - EE; d = s; }
    int pos = atomicAdd(&fill[d], 1);
    sorted[row_start[d] + pos] = s;
}

// ================= conversions =================
__global__ void convert_f32_bf16(const float* __restrict__ in, ushort* __restrict__ out, long n4) {
    long i = (long)blockIdx.x * 256 + threadIdx.x;
    if (i < n4) {
        float4 v = *(const float4*)&in[i * 4];
        ushort4 o;
        o.x = f2bf(v.x); o.y = f2bf(v.y); o.z = f2bf(v.z); o.w = f2bf(v.w);
        *(ushort4*)&out[i * 4] = o;
    }
}
__global__ void transpose_w(const float* __restrict__ W, ushort* __restrict__ Bt, int M, int K) {
    int idx = blockIdx.x * 256 + threadIdx.x;
    if (idx < M * K) {
        int m = idx / K, n = idx % K;
        Bt[n * M + m] = f2bf(W[idx]);
    }
}

// ================= bf16 MFMA GEMM =================
// C[N x K] = A[N x M] @ B[M x K]; A bf16 row-major, Bt bf16 [K][M], C bf16.
__global__ __launch_bounds__(256) void gemm_mfma(
        const ushort* __restrict__ A, const ushort* __restrict__ Bt,
        ushort* __restrict__ C, int M, int K) {
    __shared__ ushort As[64][40];
    __shared__ ushort Bs[64][40];
    int t = threadIdx.x;
    int w = t >> 6;
    int l = t & 63;
    int rowBase = blockIdx.y * 64;
    int colBase = blockIdx.x * 64;
    int srow = t >> 2;
    int sk = (t & 3) * 8;
    int m = l & 15, q = l >> 4;
    f32x4 acc[4] = {};
    for (int k0 = 0; k0 < M; k0 += 32) {
        uint4 av = make_uint4(0u, 0u, 0u, 0u);
        int gr = rowBase + srow;
        if (gr < NN) av = *(const uint4*)&A[(long)gr * M + k0 + sk];
        uint4 bv = *(const uint4*)&Bt[(long)(colBase + srow) * M + k0 + sk];
        *(uint4*)&As[srow][sk] = av;
        *(uint4*)&Bs[srow][sk] = bv;
        __syncthreads();
        short8 af = *(const short8*)&As[w * 16 + m][q * 8];
#pragma unroll
        for (int c = 0; c < 4; ++c) {
            short8 bf = *(const short8*)&Bs[c * 16 + m][q * 8];
            acc[c] = __builtin_amdgcn_mfma_f32_16x16x32_bf16(af, bf, acc[c], 0, 0, 0);
        }
        __syncthreads();
    }
#pragma unroll
    for (int c = 0; c < 4; ++c) {
#pragma unroll
        for (int r = 0; r < 4; ++r) {
            int orow = rowBase + w * 16 + q * 4 + r;
            if (orow < NN) C[(long)orow * K + colBase + c * 16 + m] = f2bf(acc[c][r]);
        }
    }
}

// ================= GCN gather (bf16 h, 4-way unroll) =================
__global__ __launch_bounds__(256) void gcn_gather(
        const int* __restrict__ row_start, const int* __restrict__ sorted,
        const float* __restrict__ dinv, const ushort* __restrict__ h0,
        float* __restrict__ agg) {
    int node = blockIdx.x * 4 + (threadIdx.x >> 6);
    if (node >= NN) return;
    int c = threadIdx.x & 63;
    int b = row_start[node], e = row_start[node + 1];
    float a0 = 0.f, a1 = 0.f, a2 = 0.f, a3 = 0.f;
    int i = b;
    for (; i + 3 < e; i += 4) {
        int s0 = sorted[i], s1 = sorted[i + 1], s2 = sorted[i + 2], s3 = sorted[i + 3];
        a0 += bf2f(h0[(long)s0 * 64 + c]) * dinv[s0];
        a1 += bf2f(h0[(long)s1 * 64 + c]) * dinv[s1];
        a2 += bf2f(h0[(long)s2 * 64 + c]) * dinv[s2];
        a3 += bf2f(h0[(long)s3 * 64 + c]) * dinv[s3];
    }
    for (; i < e; ++i) {
        int s0 = sorted[i];
        a0 += bf2f(h0[(long)s0 * 64 + c]) * dinv[s0];
    }
    agg[(long)node * 64 + c] = (a0 + a1 + a2 + a3) * dinv[node];
}

// ================= BatchNorm =================
// C=64, fp32 input, relu pre-BN. grid = ceil(NN/64), block 256.
__global__ __launch_bounds__(256) void bn_stats64(
        const float* __restrict__ x, const float* __restrict__ bias,
        float* __restrict__ sums, float* __restrict__ sumsq) {
    __shared__ float red[512];
    int t = threadIdx.x;
    int col = t & 63, sub = t >> 6;
    int r0 = blockIdx.x * 64;
    int r1 = min(r0 + 64, NN);
    float b = bias[col];
    float s = 0.f, ss = 0.f;
    for (int r = r0 + sub; r < r1; r += 4) {
        float v = fmaxf(x[(long)r * 64 + col] + b, 0.f);
        s += v; ss += v * v;
    }
    red[t] = s; red[256 + t] = ss;
    __syncthreads();
    if (t < 64) {
        s = red[t] + red[t + 64] + red[t + 128] + red[t + 192];
        ss = red[256 + t] + red[320 + t] + red[384 + t] + red[448 + t];
        atomicAdd(&sums[col], s);
        atomicAdd(&sumsq[col], ss);
    }
}
// C=256, bf16 input, no relu. grid = ceil(NN/32), block 256.
__global__ __launch_bounds__(256) void bn_stats256(
        const ushort* __restrict__ x, const float* __restrict__ bias,
        float* __restrict__ sums, float* __restrict__ sumsq) {
    int t = threadIdx.x;
    int r0 = blockIdx.x * 32;
    int r1 = min(r0 + 32, NN);
    float b = bias[t];
    float s = 0.f, ss = 0.f;
    for (int r = r0; r < r1; ++r) {
        float v = bf2f(x[(long)r * 256 + t]) + b;
        s += v; ss += v * v;
    }
    atomicAdd(&sums[t], s);
    atomicAdd(&sumsq[t], ss);
}
__global__ void bn_finalize(const float* __restrict__ sums, const float* __restrict__ sumsq,
                            const float* __restrict__ g, const float* __restrict__ beta,
                            float* __restrict__ scale, float* __restrict__ shift, int C) {
    int c = threadIdx.x;
    if (c < C) {
        float mean = sums[c] / (float)NN;
        float var = sumsq[c] / (float)NN - mean * mean;
        float sc = g[c] * rsqrtf(var + BN_EPS);
        scale[c] = sc;
        shift[c] = beta[c] - mean * sc;
    }
}
// GCN: fp32 in, relu pre-BN, bf16 out
__global__ void bn_apply_gcn(const float* __restrict__ x, const float* __restrict__ bias,
                             const float* __restrict__ scale, const float* __restrict__ shift,
                             ushort* __restrict__ out) {
    long idx = (long)blockIdx.x * 256 + threadIdx.x;
    if (idx < (long)NN * 64) {
        int c = (int)(idx & 63);
        float v = fmaxf(x[idx] + bias[c], 0.f);
        out[idx] = f2bf(scale[c] * v + shift[c]);
    }
}
// GAT: bf16 in, ELU post-BN, bf16 or fp32 out
__global__ void bn_apply_gat(const ushort* __restrict__ x, const float* __restrict__ bias,
                             const float* __restrict__ scale, const float* __restrict__ shift,
                             void* __restrict__ out, int out_bf16) {
    long idx = (long)blockIdx.x * 256 + threadIdx.x;
    if (idx < (long)NN * 256) {
        int c = (int)(idx & 255);
        float v = bf2f(x[idx]) + bias[c];
        v = scale[c] * v + shift[c];
        v = (v > 0.f) ? v : expm1f(v);
        if (out_bf16) ((ushort*)out)[idx] = f2bf(v);
        else ((float*)out)[idx] = v;
    }
}

// ================= GAT =================
__global__ void gat_alpha(const ushort* __restrict__ h, const float* __restrict__ a_src,
                          const float* __restrict__ a_dst,
                          float* __restrict__ alpha_s, float* __restrict__ alpha_d) {
    int n = blockIdx.x;
    int t = threadIdx.x;
    float hv = bf2f(h[(long)n * 256 + t]);
    float vs = hv * a_src[t];
    float vd = hv * a_dst[t];
    for (int off = 32; off > 0; off >>= 1) {
        vs += __shfl_down(vs, off);
        vd += __shfl_down(vd, off);
    }
    if ((t & 63) == 0) {
        int head = t >> 6;
        alpha_s[n * 4 + head] = vs;
        alpha_d[n * 4 + head] = vd;
    }
}

// one wave per node; lane = edge_k*4 + head; shuffle-butterfly softmax; no barriers.
__global__ __launch_bounds__(256) void gat_att(
        const int* __restrict__ row_start, const int* __restrict__ sorted,
        const float* __restrict__ as, const float* __restrict__ ad,
        float* __restrict__ att) {
    int node = blockIdx.x * 4 + (threadIdx.x >> 6);
    if (node >= NN) return;
    int l = threadIdx.x & 63;
    int h = l & 3, k = l >> 2;
    int b = row_start[node], e = row_start[node + 1];
    float adn = ad[node * 4 + h];
    // pass 1: per-head max
    float lm = -1e30f;
    for (int i = b + k; i < e; i += 16) {
        int s = sorted[i];
        float ev = as[s * 4 + h] + adn;
        ev = (ev > 0.f) ? ev : NEG_SLOPE * ev;
        lm = fmaxf(lm, ev);
    }
    lm = fmaxf(lm, __shfl_xor(lm, 4));
    lm = fmaxf(lm, __shfl_xor(lm, 8));
    lm = fmaxf(lm, __shfl_xor(lm, 16));
    lm = fmaxf(lm, __shfl_xor(lm, 32));
    // pass 2: exp, store unnormalized, per-head sum
    float ls = 0.f;
    for (int i = b + k; i < e; i += 16) {
        int s = sorted[i];
        float ev = as[s * 4 + h] + adn;
        ev = (ev > 0.f) ? ev : NEG_SLOPE * ev;
        float wv = __expf(ev - lm);
        att[(long)i * 4 + h] = wv;
        ls += wv;
    }
    ls += __shfl_xor(ls, 4);
    ls += __shfl_xor(ls, 8);
    ls += __shfl_xor(ls, 16);
    ls += __shfl_xor(ls, 32);
    float inv = 1.0f / ls;
    // pass 3: normalize
    for (int i = b + k; i < e; i += 16) {
        att[(long)i * 4 + h] *= inv;
    }
}

// one block per node: pure weighted gather, 4-way unrolled, bf16 out
__global__ __launch_bounds__(256) void gat_gather(
        const int* __restrict__ row_start, const int* __restrict__ sorted,
        const float* __restrict__ att, const ushort* __restrict__ h,
        ushort* __restrict__ out) {
    int n = blockIdx.x;
    int t = threadIdx.x;
    int b = row_start[n], e = row_start[n + 1];
    int head = t >> 6;                      // wave-uniform
    float a0 = 0.f, a1 = 0.f, a2 = 0.f, a3 = 0.f;
    int i = b;
    for (; i + 3 < e; i += 4) {
        int s0 = sorted[i], s1 = sorted[i + 1], s2 = sorted[i + 2], s3 = sorted[i + 3];
        float w0 = att[(long)i * 4 + head];
        float w1 = att[(long)(i + 1) * 4 + head];
        float w2 = att[(long)(i + 2) * 4 + head];
        float w3 = att[(long)(i + 3) * 4 + head];
        a0 += w0 * bf2f(h[(long)s0 * 256 + t]);
        a1 += w1 * bf2f(h[(long)s1 * 256 + t]);
        a2 += w2 * bf2f(h[(long)s2 * 256 + t]);
        a3 += w3 * bf2f(h[(long)s3 * 256 + t]);
    }
    for (; i < e; ++i) {
        int s0 = sorted[i];
        a0 += att[(long)i * 4 + head] * bf2f(h[(long)s0 * 256 + t]);
    }
    out[(long)n * 256 + t] = f2bf(a0 + a1 + a2 + a3);
}

// ================= launch =================
extern "C" void kernel_launch(void* const* d_in, const int* in_sizes, int n_in,
                              void* d_out, int out_size, void* d_ws, size_t ws_size,
                              hipStream_t stream) {
    const float* x      = (const float*)d_in[0];
    const int*   ei     = (const int*)d_in[1];
    const float* W_gcn  = (const float*)d_in[2];
    const float* b_gcn  = (const float*)d_in[3];
    const float* g0     = (const float*)d_in[4];
    const float* beta0  = (const float*)d_in[5];
    const float* W1     = (const float*)d_in[6];
    const float* a_src1 = (const float*)d_in[7];
    const float* a_dst1 = (const float*)d_in[8];
    const float* b1     = (const float*)d_in[9];
    const float* g1     = (const float*)d_in[10];
    const float* beta1  = (const float*)d_in[11];
    const float* W2     = (const float*)d_in[12];
    const float* a_src2 = (const float*)d_in[13];
    const float* a_dst2 = (const float*)d_in[14];
    const float* b2     = (const float*)d_in[15];
    const float* g2     = (const float*)d_in[16];
    const float* beta2  = (const float*)d_in[17];

    const long N = NN;
    float* ws = (float*)d_ws;

    // ---- layout (~540N floats = 216 MB; ws proven >= 641N floats in R1) ----
    // NOTE R4 bug: yb is [N,256] ushort = 128N floats (not 64N) — attb moved past it.
    float* dinv    = ws;                        // N
    float* alpha_s = ws + N;                    // 4N
    float* alpha_d = ws + 5 * N;                // 4N
    float* sums    = ws + 9 * N;                // 256
    float* sumsq   = sums + 256;
    float* scale   = sumsq + 256;
    float* shift   = scale + 256;
    int*   row_start = (int*)(shift + 256);     // N+1
    int*   fill      = row_start + NN + 1;      // N
    int*   deg_i     = fill + NN;               // N
    int*   sorted    = deg_i + NN;              // 9N
    int*   bsum      = sorted + EE + NN;        // ~400
    ushort* Wgt  = (ushort*)(ws + 23 * N);      // 64x256
    ushort* W1t  = Wgt + 16384;                 // 256x64
    ushort* W2t  = W1t + 16384;                 // 256x256
    ushort* h0b  = (ushort*)(ws + 24 * N);      // [N,64] bf16 (32N fl); reused as x1b
    ushort* x1b  = h0b;
    float*  agg0 = ws + 56 * N;                 // [N,64] fp32 (64N fl)
    ushort* h1b  = (ushort*)(ws + 120 * N);     // [N,256] bf16 (128N fl); also h2
    ushort* x2b  = (ushort*)(ws + 248 * N);     // [N,256] bf16 (128N fl)
    ushort* xb   = x2b;                         // alias: x bf16, dead before x2b live
    ushort* yb   = (ushort*)(ws + 376 * N);     // [N,256] bf16 gather out (128N fl)
    float*  attb = ws + 504 * N;                // (E+N)*4 floats (36N fl) -> ends 540N
    float*  outp = (float*)d_out;

    const int BLK = 256;
    dim3 blk(BLK);
    const int NBLK_N = (NN + 255) / 256;        // 391

    // ===== CSR build =====
    hipMemsetAsync(fill, 0, 2L * NN * sizeof(int), stream);
    hist_kernel<<<(EE + 255) / 256, blk, 0, stream>>>(ei, deg_i);
    dinv_kernel<<<NBLK_N, blk, 0, stream>>>(deg_i, dinv);
    scan_k1<<<NBLK_N, blk, 0, stream>>>(deg_i, row_start, bsum);
    scan_k2<<<1, 512, 0, stream>>>(bsum, NBLK_N);
    scan_k3<<<(NN + 1 + 255) / 256, blk, 0, stream>>>(row_start, bsum);
    scatter_kernel<<<(EE + NN + 255) / 256, blk, 0, stream>>>(ei, row_start, fill, sorted);

    // ===== conversions =====
    convert_f32_bf16<<<(int)((N * 256 / 4 + 255) / 256), blk, 0, stream>>>(x, xb, N * 256 / 4);
    transpose_w<<<(FIN * CH + 255) / 256, blk, 0, stream>>>(W_gcn, Wgt, FIN, CH);
    transpose_w<<<(CH * C1 + 255) / 256, blk, 0, stream>>>(W1, W1t, CH, C1);
    transpose_w<<<(C1 * C1 + 255) / 256, blk, 0, stream>>>(W2, W2t, C1, C1);

    // ===== GCN =====
    gemm_mfma<<<dim3(CH / 64, (NN + 63) / 64), blk, 0, stream>>>(xb, Wgt, h0b, FIN, CH);
    gcn_gather<<<(NN + 3) / 4, blk, 0, stream>>>(row_start, sorted, dinv, h0b, agg0);
    hipMemsetAsync(sums, 0, 512 * sizeof(float), stream);
    bn_stats64<<<(NN + 63) / 64, blk, 0, stream>>>(agg0, b_gcn, sums, sumsq);
    bn_finalize<<<1, CH, 0, stream>>>(sums, sumsq, g0, beta0, scale, shift, CH);
    bn_apply_gcn<<<(int)(N * CH / BLK), blk, 0, stream>>>(agg0, b_gcn, scale, shift, x1b);

    // ===== GAT layer 1 =====
    gemm_mfma<<<dim3(C1 / 64, (NN + 63) / 64), blk, 0, stream>>>(x1b, W1t, h1b, CH, C1);
    gat_alpha<<<NN, blk, 0, stream>>>(h1b, a_src1, a_dst1, alpha_s, alpha_d);
    gat_att<<<(NN + 3) / 4, blk, 0, stream>>>(row_start, sorted, alpha_s, alpha_d, attb);
    gat_gather<<<NN, blk, 0, stream>>>(row_start, sorted, attb, h1b, yb);
    hipMemsetAsync(sums, 0, 512 * sizeof(float), stream);
    bn_stats256<<<(NN + 31) / 32, blk, 0, stream>>>(yb, b1, sums, sumsq);
    bn_finalize<<<1, C1, 0, stream>>>(sums, sumsq, g1, beta1, scale, shift, C1);
    bn_apply_gat<<<(int)(N * C1 / BLK), blk, 0, stream>>>(yb, b1, scale, shift, x2b, 1);

    // ===== GAT layer 2 =====
    gemm_mfma<<<dim3(C1 / 64, (NN + 63) / 64), blk, 0, stream>>>(x2b, W2t, h1b, C1, C1);
    gat_alpha<<<NN, blk, 0, stream>>>(h1b, a_src2, a_dst2, alpha_s, alpha_d);
    gat_att<<<(NN + 3) / 4, blk, 0, stream>>>(row_start, sorted, alpha_s, alpha_d, attb);
    gat_gather<<<NN, blk, 0, stream>>>(row_start, sorted, attb, h1b, yb);
    hipMemsetAsync(sums, 0, 512 * sizeof(float), stream);
    bn_stats256<<<(NN + 31) / 32, blk, 0, stream>>>(yb, b2, sums, sumsq);
    bn_finalize<<<1, C1, 0, stream>>>(sums, sumsq, g2, beta2, scale, shift, C1);
    bn_apply_gat<<<(int)(N * C1 / BLK), blk, 0, stream>>>(yb, b2, scale, shift, outp, 0);
}